// Round 10
// baseline (202.377 us; speedup 1.0000x reference)
//
#include <hip/hip_runtime.h>
#include <math.h>

constexpr int NN  = 50000;   // nodes
constexpr int NE  = 800000;  // edges
constexpr int IND = 128;     // input dim
constexpr int HCD = 128;     // heads*channels

// fine-bucket CSR geometry
constexpr int NBKT = 250;              // dst-range buckets
constexpr int NPB  = 200;              // nodes per bucket (250*200 = 50000)
constexpr int BCAP = 4096;             // staging cap/bucket (mean 3200)
constexpr int BE   = 2048;             // edges per bucket_kernel block
constexpr int EPT  = BE / 256;         // 8 edges per thread
constexpr int B1B  = (NE + BE - 1) / BE;   // 391 blocks

typedef __attribute__((ext_vector_type(8))) short bf16x8;
typedef __attribute__((ext_vector_type(4))) float f32x4;
typedef __attribute__((ext_vector_type(2))) float f32x2;

__device__ __forceinline__ void splitbf(float f, unsigned short &h, unsigned short &lo) {
    unsigned u = __float_as_uint(f);
    h = (unsigned short)(u >> 16);
    float fh = __uint_as_float(u & 0xffff0000u);
    lo = (unsigned short)(__float_as_uint(f - fh) >> 16);
}
__device__ __forceinline__ unsigned short bf16rne(float f) {
    unsigned u = __float_as_uint(f);
    u += 0x7fffu + ((u >> 16) & 1u);
    return (unsigned short)(u >> 16);
}
__device__ __forceinline__ float bf2f(unsigned short u) {
    return __uint_as_float(((unsigned)u) << 16);
}

// ---------------------------------------------------------------------------
// K1: MFMA split-bf16 GEMM.  grid.y==0: xl_bf16 = bf16(x@Wl + bl)
//                            grid.y==1: xr      = x@Wr + br  (fp32)
// ---------------------------------------------------------------------------
constexpr int BM = 128;
constexpr int BK = 64;

__global__ __launch_bounds__(256) void gemm_mfma(
    const float* __restrict__ x, const float* __restrict__ Wl,
    const float* __restrict__ Wr, const float* __restrict__ bl,
    const float* __restrict__ br, unsigned short* __restrict__ xlbf,
    float* __restrict__ xr)
{
    extern __shared__ char smem[];      // 48 KB
    char* Ah = smem;                    // [128][64] bf16
    char* Al = smem + 16384;
    char* Bh = smem + 32768;            // [c=128][k=64] bf16 (W transposed)

    const int tid = threadIdx.x;
    const float* W  = blockIdx.y ? Wr : Wl;
    const float* bv = blockIdx.y ? br : bl;
    const int bn = blockIdx.x * BM;

    const int l   = tid & 63;
    const int wid = tid >> 6;
    const int wr  = (wid >> 1) * 64;
    const int wc  = (wid & 1) * 64;
    const int lr  = l & 15;
    const int kg  = l >> 4;

    f32x4 acc[4][4];
#pragma unroll
    for (int s = 0; s < 4; ++s)
#pragma unroll
        for (int f = 0; f < 4; ++f) acc[s][f] = (f32x4){0.f, 0.f, 0.f, 0.f};

    const int cB  = tid & 127;
    const int khB = tid >> 7;

    for (int ki = 0; ki < 2; ++ki) {
#pragma unroll
        for (int r = 0; r < 8; ++r) {
            int g = tid + r * 256;
            int row = g >> 4, k4 = g & 15;
            int node = bn + row;
            float4 v = make_float4(0.f, 0.f, 0.f, 0.f);
            if (node < NN) v = *(const float4*)&x[node * IND + ki * BK + k4 * 4];
            unsigned short h0, h1, h2, h3, q0, q1, q2, q3;
            splitbf(v.x, h0, q0); splitbf(v.y, h1, q1);
            splitbf(v.z, h2, q2); splitbf(v.w, h3, q3);
            int off = (row * BK + k4 * 4) * 2;
            int swz = off ^ ((row & 7) << 4);
            *(ushort4*)(Ah + swz) = make_ushort4(h0, h1, h2, h3);
            *(ushort4*)(Al + swz) = make_ushort4(q0, q1, q2, q3);
        }
#pragma unroll
        for (int r = 0; r < 8; ++r) {
            int kb = r * 8 + khB * 4;
            float f0 = W[(ki * BK + kb + 0) * HCD + cB];
            float f1 = W[(ki * BK + kb + 1) * HCD + cB];
            float f2 = W[(ki * BK + kb + 2) * HCD + cB];
            float f3 = W[(ki * BK + kb + 3) * HCD + cB];
            int off = (cB * BK + kb) * 2;
            int swz = off ^ ((cB & 7) << 4);
            *(ushort4*)(Bh + swz) = make_ushort4(bf16rne(f0), bf16rne(f1),
                                                 bf16rne(f2), bf16rne(f3));
        }
        __syncthreads();
#pragma unroll
        for (int kk = 0; kk < 2; ++kk) {
            bf16x8 Bfh[4];
#pragma unroll
            for (int f = 0; f < 4; ++f) {
                int c = wc + f * 16 + lr;
                int swz = (c * 128 + kk * 64 + kg * 16) ^ ((c & 7) << 4);
                Bfh[f] = *(const bf16x8*)(Bh + swz);
            }
#pragma unroll
            for (int s = 0; s < 4; ++s) {
                int row = wr + s * 16 + lr;
                int swz = (row * 128 + kk * 64 + kg * 16) ^ ((row & 7) << 4);
                bf16x8 Afh = *(const bf16x8*)(Ah + swz);
                bf16x8 Afl = *(const bf16x8*)(Al + swz);
#pragma unroll
                for (int f = 0; f < 4; ++f) {
                    acc[s][f] = __builtin_amdgcn_mfma_f32_16x16x32_bf16(Afh, Bfh[f], acc[s][f], 0, 0, 0);
                    acc[s][f] = __builtin_amdgcn_mfma_f32_16x16x32_bf16(Afl, Bfh[f], acc[s][f], 0, 0, 0);
                }
            }
        }
        __syncthreads();
    }
#pragma unroll
    for (int s = 0; s < 4; ++s)
#pragma unroll
        for (int f = 0; f < 4; ++f) {
            int c = wc + f * 16 + lr;
            float bb = bv[c];
#pragma unroll
            for (int j = 0; j < 4; ++j) {
                int r = bn + wr + s * 16 + kg * 4 + j;
                if (r >= NN) continue;
                float v = acc[s][f][j] + bb;
                if (blockIdx.y) xr[r * HCD + c] = v;
                else            xlbf[r * HCD + c] = bf16rne(v);
            }
        }
}

// ---------------------------------------------------------------------------
// K2: bucket scatter. LDS count -> one global grant per touched bucket ->
// compacted packed int2 (src|dloc<<17, ea). NO per-node atomics.
// ---------------------------------------------------------------------------
__global__ __launch_bounds__(256) void bucket_kernel(
    const int* __restrict__ src, const int* __restrict__ dst,
    const float* __restrict__ ea, int* __restrict__ gcur,
    int2* __restrict__ stg)
{
    __shared__ int cnt[NBKT], base[NBKT];
    const int tid = threadIdx.x;
    for (int j = tid; j < NBKT; j += 256) cnt[j] = 0;
    __syncthreads();

    const int e0 = blockIdx.x * BE;
    int w0[EPT], w1[EPT]; int nb[EPT];
#pragma unroll
    for (int j = 0; j < EPT; ++j) {
        int e = e0 + j * 256 + tid;
        bool ok = e < NE;
        int s_ = ok ? src[e] : 0;
        int d_ = ok ? dst[e] : 0;
        float a_ = ok ? ea[e] : 0.f;
        int b  = d_ / NPB;
        int dl = d_ - b * NPB;
        w0[j] = s_ | (dl << 17);
        w1[j] = __float_as_int(a_);
        nb[j] = ok ? b : -1;
        if (ok) atomicAdd(&cnt[b], 1);
    }
    __syncthreads();
    for (int j = tid; j < NBKT; j += 256) {
        base[j] = cnt[j] ? atomicAdd(&gcur[j], cnt[j]) : 0;
        cnt[j] = 0;                      // reuse as local cursor
    }
    __syncthreads();
#pragma unroll
    for (int j = 0; j < EPT; ++j) {
        if (nb[j] >= 0) {
            int slot = base[nb[j]] + atomicAdd(&cnt[nb[j]], 1);
            if (slot < BCAP)
                stg[nb[j] * BCAP + slot] = make_int2(w0[j], w1[j]);
        }
    }
}

// ---------------------------------------------------------------------------
// K3: exclusive scan of 250 bucket counts (single block)
// ---------------------------------------------------------------------------
__global__ __launch_bounds__(256) void bscan(const int* __restrict__ gcur,
                                             int* __restrict__ bbase,
                                             int* __restrict__ off)
{
    __shared__ int t[256];
    int tid = threadIdx.x;
    int v = (tid < NBKT) ? gcur[tid] : 0;
    t[tid] = v;
    __syncthreads();
    for (int d = 1; d < 256; d <<= 1) {
        int u = (tid >= d) ? t[tid - d] : 0;
        __syncthreads();
        t[tid] += u;
        __syncthreads();
    }
    if (tid < NBKT) bbase[tid] = t[tid] - v;
    if (tid == 0) off[NN] = NE;
}

// ---------------------------------------------------------------------------
// K4: per-bucket CSR build (LDS histogram + scan; no global atomics)
// ---------------------------------------------------------------------------
__global__ __launch_bounds__(256) void csr_build(
    const int2* __restrict__ stg, const int* __restrict__ gcur,
    const int* __restrict__ bbase, int* __restrict__ off,
    int2* __restrict__ csr)
{
    __shared__ int hist[NPB], t[256], cur[NPB];
    const int b = blockIdx.x, tid = threadIdx.x;
    const int count = min(gcur[b], BCAP);
    const int base  = bbase[b];

    if (tid < NPB) { hist[tid] = 0; cur[tid] = 0; }
    __syncthreads();
    for (int sl = tid; sl < count; sl += 256)
        atomicAdd(&hist[(unsigned)stg[b * BCAP + sl].x >> 17], 1);
    __syncthreads();

    int hv = (tid < NPB) ? hist[tid] : 0;
    t[tid] = hv;
    __syncthreads();
    for (int d = 1; d < 256; d <<= 1) {
        int u = (tid >= d) ? t[tid - d] : 0;
        __syncthreads();
        t[tid] += u;
        __syncthreads();
    }
    if (tid < NPB) off[b * NPB + tid] = base + t[tid] - hv;   // exclusive
    __syncthreads();

    for (int sl = tid; sl < count; sl += 256) {
        int2 v = stg[b * BCAP + sl];
        int dl = (unsigned)v.x >> 17;
        int pos = base + (t[dl] - hist[dl]) + atomicAdd(&cur[dl], 1);
        csr[pos] = make_int2(v.x & 0x1ffff, v.y);
    }
}

// ---------------------------------------------------------------------------
// K5: node kernel, 1 wave = 1 node; packed-fp32 (f32x2 -> v_pk_*) math.
// Lane l = 16*g + i: group g handles edge quad-slot g, lane i owns channels
// [8i,8i+8) as 4 float2 pairs. Output written as bf16.
// ---------------------------------------------------------------------------
__global__ __launch_bounds__(256) void node_kernel(
    const unsigned short* __restrict__ xlbf, const float* __restrict__ xr,
    const float* __restrict__ We, const float* __restrict__ att,
    const int* __restrict__ off, const int2* __restrict__ csr,
    unsigned short* __restrict__ out_bf)
{
    const int n = blockIdx.x * 4 + (threadIdx.x >> 6);
    if (n >= NN) return;
    const int l  = threadIdx.x & 63;
    const int g  = l >> 4;
    const int i  = l & 15;
    const int c0 = i * 8;

    f32x2 wev[4], atv[4], xrv[4];
#pragma unroll
    for (int j = 0; j < 4; ++j) {
        wev[j] = (f32x2){We[c0 + 2 * j], We[c0 + 2 * j + 1]};
        atv[j] = (f32x2){att[c0 + 2 * j], att[c0 + 2 * j + 1]};
        xrv[j] = (f32x2){xr[(size_t)n * HCD + c0 + 2 * j],
                         xr[(size_t)n * HCD + c0 + 2 * j + 1]};
    }

    const int s = off[n], e = off[n + 1];
    if (s == e) {
        if (g == 0) {
            uint4 z = make_uint4(0, 0, 0, 0);
            *(uint4*)&out_bf[(size_t)n * HCD + c0] = z;
        }
        return;
    }

    float mx = -3.0e38f, sm = 0.f;
    f32x2 acc[4];
#pragma unroll
    for (int j = 0; j < 4; ++j) acc[j] = (f32x2){0.f, 0.f};

    int k = s;
    int2 c2; uint4 xb; bool v;
    {
        int idx = min(k + g, e - 1);
        c2 = csr[idx];
        xb = *(const uint4*)&xlbf[(size_t)c2.x * HCD + c0];
        v  = (k + g) < e;
    }

    for (; k < e; k += 4) {
        int2 c2n; uint4 xbn; bool vn;
        {
            int idx = min(k + 4 + g, e - 1);
            c2n = csr[idx];
            xbn = *(const uint4*)&xlbf[(size_t)c2n.x * HCD + c0];
            vn  = (k + 4 + g) < e;
        }
        f32x2 xv[4];
        xv[0] = (f32x2){__uint_as_float(xb.x << 16), __uint_as_float(xb.x & 0xffff0000u)};
        xv[1] = (f32x2){__uint_as_float(xb.y << 16), __uint_as_float(xb.y & 0xffff0000u)};
        xv[2] = (f32x2){__uint_as_float(xb.z << 16), __uint_as_float(xb.z & 0xffff0000u)};
        xv[3] = (f32x2){__uint_as_float(xb.w << 16), __uint_as_float(xb.w & 0xffff0000u)};

        float eaf = __int_as_float(c2.y);
        f32x2 p2 = (f32x2){0.f, 0.f};
#pragma unroll
        for (int j = 0; j < 4; ++j) {
            f32x2 s2 = xv[j] + xrv[j];
            s2 = eaf * wev[j] + s2;                       // pk_fma
            f32x2 m2 = __builtin_elementwise_max(s2, s2 * 0.2f);  // leaky_relu
            p2 = m2 * atv[j] + p2;                        // pk_fma
        }
        float p = p2.x + p2.y;
        p += __shfl_xor(p, 1);                            // 4-lane head reduce
        p += __shfl_xor(p, 2);
        if (!v) p = -1.0e30f;

        if (__any(p > mx + 8.f)) {
            float nm = fmaxf(mx, p);
            float sc = __expf(mx - nm);
            sm *= sc;
#pragma unroll
            for (int j = 0; j < 4; ++j) acc[j] *= sc;
            mx = nm;
        }
        float ev = v ? __expf(p - mx) : 0.f;
        sm += ev;
#pragma unroll
        for (int j = 0; j < 4; ++j) acc[j] = ev * xv[j] + acc[j];   // pk_fma

        c2 = c2n; xb = xbn; v = vn;
    }

    // merge the 4 group states (lanes l, l^16, l^32 hold same channels)
    float M = fmaxf(mx, __shfl_xor(mx, 16));
    M = fmaxf(M, __shfl_xor(M, 32));
    float sc = __expf(mx - M);
    float smT = sm * sc;
    smT += __shfl_xor(smT, 16);
    smT += __shfl_xor(smT, 32);
    float inv = 1.f / (smT + 1e-16f);
    unsigned uo[4];
#pragma unroll
    for (int j = 0; j < 4; ++j) {
        float a0 = acc[j].x * sc, a1 = acc[j].y * sc;
        a0 += __shfl_xor(a0, 16);  a0 += __shfl_xor(a0, 32);
        a1 += __shfl_xor(a1, 16);  a1 += __shfl_xor(a1, 32);
        uo[j] = (unsigned)bf16rne(a0 * inv) | ((unsigned)bf16rne(a1 * inv) << 16);
    }
    if (g == 0)
        *(uint4*)&out_bf[(size_t)n * HCD + c0] = make_uint4(uo[0], uo[1], uo[2], uo[3]);
}

// ---------------------------------------------------------------------------
// K6: BN statistics from bf16 out (per-channel sum & sumsq)
// ---------------------------------------------------------------------------
__global__ __launch_bounds__(256) void bnstat_kernel(const unsigned short* __restrict__ out_bf,
                                                     float* __restrict__ stats)
{
    const int c = threadIdx.x & 127;
    const int h = threadIdx.x >> 7;   // 0/1
    float s = 0.f, q = 0.f;
    for (int n = blockIdx.x * 2 + h; n < NN; n += gridDim.x * 2) {
        float v = bf2f(out_bf[(size_t)n * HCD + c]);
        s += v; q += v * v;
    }
    atomicAdd(&stats[c], s);
    atomicAdd(&stats[HCD + c], q);
}

// ---------------------------------------------------------------------------
// K7: normalize + affine + ELU; bf16 in, fp32 out (8 channels/thread)
// ---------------------------------------------------------------------------
__global__ __launch_bounds__(256) void bn_elu_kernel(
    const unsigned short* __restrict__ out_bf, const float* __restrict__ stats,
    const float* __restrict__ gamma, const float* __restrict__ beta,
    float* __restrict__ out)
{
    int i8 = blockIdx.x * 256 + threadIdx.x;        // 8 channels per thread
    if (i8 >= NN * HCD / 8) return;
    int c0 = (i8 & 15) * 8;
    uint4 u = *(const uint4*)&out_bf[(size_t)i8 * 8];
    float vv[8] = {
        __uint_as_float(u.x << 16), __uint_as_float(u.x & 0xffff0000u),
        __uint_as_float(u.y << 16), __uint_as_float(u.y & 0xffff0000u),
        __uint_as_float(u.z << 16), __uint_as_float(u.z & 0xffff0000u),
        __uint_as_float(u.w << 16), __uint_as_float(u.w & 0xffff0000u)};
    float o[8];
#pragma unroll
    for (int j = 0; j < 8; ++j) {
        int c = c0 + j;
        float mean = stats[c] * (1.f / NN);
        float var  = stats[HCD + c] * (1.f / NN) - mean * mean;
        float inv  = rsqrtf(var + 1e-5f);
        float t = (vv[j] - mean) * inv * gamma[c] + beta[c];
        o[j] = (t > 0.f) ? t : expm1f(t);
    }
    float* dst = &out[(size_t)i8 * 8];
    *(float4*)dst       = make_float4(o[0], o[1], o[2], o[3]);
    *(float4*)(dst + 4) = make_float4(o[4], o[5], o[6], o[7]);
}

// ---------------------------------------------------------------------------
extern "C" void kernel_launch(void* const* d_in, const int* in_sizes, int n_in,
                              void* d_out, int out_size, void* d_ws, size_t ws_size,
                              hipStream_t stream)
{
    (void)in_sizes; (void)n_in; (void)out_size; (void)ws_size;
    const float* x    = (const float*)d_in[0];
    const int*   ei   = (const int*)  d_in[1];
    const float* ea   = (const float*)d_in[2];
    const float* Wl   = (const float*)d_in[3];
    const float* bl   = (const float*)d_in[4];
    const float* Wr   = (const float*)d_in[5];
    const float* br   = (const float*)d_in[6];
    const float* We   = (const float*)d_in[7];
    const float* att  = (const float*)d_in[8];
    const float* gamma= (const float*)d_in[10];
    const float* beta = (const float*)d_in[11];
    float* out = (float*)d_out;

    char* wsb = (char*)d_ws;
    size_t o = 0;
    auto take = [&](size_t bytes) -> char* {
        char* p = wsb + o;
        o += (bytes + 255) & ~size_t(255);
        return p;
    };
    unsigned short* xlbf  = (unsigned short*)take(sizeof(unsigned short) * NN * HCD);
    float*          xr    = (float*)take(sizeof(float) * NN * HCD);
    unsigned short* outbf = (unsigned short*)take(sizeof(unsigned short) * NN * HCD);
    int2*  csr     = (int2*) take(sizeof(int2)  * NE);
    int*   offs    = (int*)  take(sizeof(int)   * (NN + 1));
    int*   bbase   = (int*)  take(sizeof(int)   * 256);
    int2*  stg     = (int2*) take(sizeof(int2)  * NBKT * BCAP);   // 8.2 MB
    size_t zbytes  = sizeof(float) * 2 * HCD + sizeof(int) * NBKT;
    char*  zbase   = take(zbytes);
    float* stats   = (float*)zbase;
    int*   gcur    = (int*)(stats + 2 * HCD);

    hipMemsetAsync(zbase, 0, zbytes, stream);

    const int* srcI = ei;
    const int* dstI = ei + NE;

    gemm_mfma<<<dim3((NN + BM - 1) / BM, 2), 256, 49152, stream>>>(
        x, Wl, Wr, bl, br, xlbf, xr);
    bucket_kernel<<<B1B, 256, 0, stream>>>(srcI, dstI, ea, gcur, stg);
    bscan<<<1, 256, 0, stream>>>(gcur, bbase, offs);
    csr_build<<<NBKT, 256, 0, stream>>>(stg, gcur, bbase, offs, csr);
    node_kernel<<<(NN + 3) / 4, 256, 0, stream>>>(xlbf, xr, We, att, offs, csr, outbf);
    bnstat_kernel<<<512, 256, 0, stream>>>(outbf, stats);
    bn_elu_kernel<<<(NN * HCD / 8 + 255) / 256, 256, 0, stream>>>(outbf, stats,
                                                                  gamma, beta, out);
}

// Round 11
// 143.114 us; speedup vs baseline: 1.4141x; 1.4141x over previous
//
#include <hip/hip_runtime.h>
#include <math.h>

constexpr int NN  = 50000;   // nodes
constexpr int NE  = 800000;  // edges
constexpr int IND = 128;     // input dim
constexpr int HCD = 128;     // heads*channels

// fine-bucket CSR geometry
constexpr int NBKT = 250;              // dst-range buckets
constexpr int NPB  = 200;              // nodes per bucket (250*200 = 50000)
constexpr int BCAP = 4096;             // staging cap/bucket (mean 3200)
constexpr int BE   = 2048;             // edges per bucket_kernel block
constexpr int EPT  = BE / 256;         // 8 edges per thread
constexpr int B1B  = (NE + BE - 1) / BE;   // 391 blocks

typedef __attribute__((ext_vector_type(8))) short bf16x8;
typedef __attribute__((ext_vector_type(4))) float f32x4;
typedef __attribute__((ext_vector_type(2))) float f32x2;

__device__ __forceinline__ void splitbf(float f, unsigned short &h, unsigned short &lo) {
    unsigned u = __float_as_uint(f);
    h = (unsigned short)(u >> 16);
    float fh = __uint_as_float(u & 0xffff0000u);
    lo = (unsigned short)(__float_as_uint(f - fh) >> 16);
}
__device__ __forceinline__ unsigned short bf16rne(float f) {
    unsigned u = __float_as_uint(f);
    u += 0x7fffu + ((u >> 16) & 1u);
    return (unsigned short)(u >> 16);
}

// ---------------------------------------------------------------------------
// K1: MFMA split-bf16 GEMM.  grid.y==0: xl_bf16 = bf16(x@Wl + bl)
//                            grid.y==1: xr      = x@Wr + br  (fp32)
// ---------------------------------------------------------------------------
constexpr int BM = 128;
constexpr int BK = 64;

__global__ __launch_bounds__(256) void gemm_mfma(
    const float* __restrict__ x, const float* __restrict__ Wl,
    const float* __restrict__ Wr, const float* __restrict__ bl,
    const float* __restrict__ br, unsigned short* __restrict__ xlbf,
    float* __restrict__ xr)
{
    extern __shared__ char smem[];      // 48 KB
    char* Ah = smem;                    // [128][64] bf16
    char* Al = smem + 16384;
    char* Bh = smem + 32768;            // [c=128][k=64] bf16 (W transposed)

    const int tid = threadIdx.x;
    const float* W  = blockIdx.y ? Wr : Wl;
    const float* bv = blockIdx.y ? br : bl;
    const int bn = blockIdx.x * BM;

    const int l   = tid & 63;
    const int wid = tid >> 6;
    const int wr  = (wid >> 1) * 64;
    const int wc  = (wid & 1) * 64;
    const int lr  = l & 15;
    const int kg  = l >> 4;

    f32x4 acc[4][4];
#pragma unroll
    for (int s = 0; s < 4; ++s)
#pragma unroll
        for (int f = 0; f < 4; ++f) acc[s][f] = (f32x4){0.f, 0.f, 0.f, 0.f};

    const int cB  = tid & 127;
    const int khB = tid >> 7;

    for (int ki = 0; ki < 2; ++ki) {
#pragma unroll
        for (int r = 0; r < 8; ++r) {
            int g = tid + r * 256;
            int row = g >> 4, k4 = g & 15;
            int node = bn + row;
            float4 v = make_float4(0.f, 0.f, 0.f, 0.f);
            if (node < NN) v = *(const float4*)&x[node * IND + ki * BK + k4 * 4];
            unsigned short h0, h1, h2, h3, q0, q1, q2, q3;
            splitbf(v.x, h0, q0); splitbf(v.y, h1, q1);
            splitbf(v.z, h2, q2); splitbf(v.w, h3, q3);
            int off = (row * BK + k4 * 4) * 2;
            int swz = off ^ ((row & 7) << 4);
            *(ushort4*)(Ah + swz) = make_ushort4(h0, h1, h2, h3);
            *(ushort4*)(Al + swz) = make_ushort4(q0, q1, q2, q3);
        }
#pragma unroll
        for (int r = 0; r < 8; ++r) {
            int kb = r * 8 + khB * 4;
            float f0 = W[(ki * BK + kb + 0) * HCD + cB];
            float f1 = W[(ki * BK + kb + 1) * HCD + cB];
            float f2 = W[(ki * BK + kb + 2) * HCD + cB];
            float f3 = W[(ki * BK + kb + 3) * HCD + cB];
            int off = (cB * BK + kb) * 2;
            int swz = off ^ ((cB & 7) << 4);
            *(ushort4*)(Bh + swz) = make_ushort4(bf16rne(f0), bf16rne(f1),
                                                 bf16rne(f2), bf16rne(f3));
        }
        __syncthreads();
#pragma unroll
        for (int kk = 0; kk < 2; ++kk) {
            bf16x8 Bfh[4];
#pragma unroll
            for (int f = 0; f < 4; ++f) {
                int c = wc + f * 16 + lr;
                int swz = (c * 128 + kk * 64 + kg * 16) ^ ((c & 7) << 4);
                Bfh[f] = *(const bf16x8*)(Bh + swz);
            }
#pragma unroll
            for (int s = 0; s < 4; ++s) {
                int row = wr + s * 16 + lr;
                int swz = (row * 128 + kk * 64 + kg * 16) ^ ((row & 7) << 4);
                bf16x8 Afh = *(const bf16x8*)(Ah + swz);
                bf16x8 Afl = *(const bf16x8*)(Al + swz);
#pragma unroll
                for (int f = 0; f < 4; ++f) {
                    acc[s][f] = __builtin_amdgcn_mfma_f32_16x16x32_bf16(Afh, Bfh[f], acc[s][f], 0, 0, 0);
                    acc[s][f] = __builtin_amdgcn_mfma_f32_16x16x32_bf16(Afl, Bfh[f], acc[s][f], 0, 0, 0);
                }
            }
        }
        __syncthreads();
    }
#pragma unroll
    for (int s = 0; s < 4; ++s)
#pragma unroll
        for (int f = 0; f < 4; ++f) {
            int c = wc + f * 16 + lr;
            float bb = bv[c];
#pragma unroll
            for (int j = 0; j < 4; ++j) {
                int r = bn + wr + s * 16 + kg * 4 + j;
                if (r >= NN) continue;
                float v = acc[s][f][j] + bb;
                if (blockIdx.y) xr[r * HCD + c] = v;
                else            xlbf[r * HCD + c] = bf16rne(v);
            }
        }
}

// ---------------------------------------------------------------------------
// K2: bucket scatter. LDS count -> one global grant per touched bucket ->
// compacted packed int2 (src|dloc<<17, ea). NO per-node atomics.
// ---------------------------------------------------------------------------
__global__ __launch_bounds__(256) void bucket_kernel(
    const int* __restrict__ src, const int* __restrict__ dst,
    const float* __restrict__ ea, int* __restrict__ gcur,
    int2* __restrict__ stg)
{
    __shared__ int cnt[NBKT], base[NBKT];
    const int tid = threadIdx.x;
    for (int j = tid; j < NBKT; j += 256) cnt[j] = 0;
    __syncthreads();

    const int e0 = blockIdx.x * BE;
    int w0[EPT], w1[EPT]; int nb[EPT];
#pragma unroll
    for (int j = 0; j < EPT; ++j) {
        int e = e0 + j * 256 + tid;
        bool ok = e < NE;
        int s_ = ok ? src[e] : 0;
        int d_ = ok ? dst[e] : 0;
        float a_ = ok ? ea[e] : 0.f;
        int b  = d_ / NPB;
        int dl = d_ - b * NPB;
        w0[j] = s_ | (dl << 17);
        w1[j] = __float_as_int(a_);
        nb[j] = ok ? b : -1;
        if (ok) atomicAdd(&cnt[b], 1);
    }
    __syncthreads();
    for (int j = tid; j < NBKT; j += 256) {
        base[j] = cnt[j] ? atomicAdd(&gcur[j], cnt[j]) : 0;
        cnt[j] = 0;                      // reuse as local cursor
    }
    __syncthreads();
#pragma unroll
    for (int j = 0; j < EPT; ++j) {
        if (nb[j] >= 0) {
            int slot = base[nb[j]] + atomicAdd(&cnt[nb[j]], 1);
            if (slot < BCAP)
                stg[nb[j] * BCAP + slot] = make_int2(w0[j], w1[j]);
        }
    }
}

// ---------------------------------------------------------------------------
// K3: exclusive scan of 250 bucket counts (single block)
// ---------------------------------------------------------------------------
__global__ __launch_bounds__(256) void bscan(const int* __restrict__ gcur,
                                             int* __restrict__ bbase,
                                             int* __restrict__ off)
{
    __shared__ int t[256];
    int tid = threadIdx.x;
    int v = (tid < NBKT) ? gcur[tid] : 0;
    t[tid] = v;
    __syncthreads();
    for (int d = 1; d < 256; d <<= 1) {
        int u = (tid >= d) ? t[tid - d] : 0;
        __syncthreads();
        t[tid] += u;
        __syncthreads();
    }
    if (tid < NBKT) bbase[tid] = t[tid] - v;
    if (tid == 0) off[NN] = NE;
}

// ---------------------------------------------------------------------------
// K4: per-bucket CSR build (LDS histogram + scan; no global atomics)
// ---------------------------------------------------------------------------
__global__ __launch_bounds__(256) void csr_build(
    const int2* __restrict__ stg, const int* __restrict__ gcur,
    const int* __restrict__ bbase, int* __restrict__ off,
    int2* __restrict__ csr)
{
    __shared__ int hist[NPB], t[256], cur[NPB];
    const int b = blockIdx.x, tid = threadIdx.x;
    const int count = min(gcur[b], BCAP);
    const int base  = bbase[b];

    if (tid < NPB) { hist[tid] = 0; cur[tid] = 0; }
    __syncthreads();
    for (int sl = tid; sl < count; sl += 256)
        atomicAdd(&hist[(unsigned)stg[b * BCAP + sl].x >> 17], 1);
    __syncthreads();

    int hv = (tid < NPB) ? hist[tid] : 0;
    t[tid] = hv;
    __syncthreads();
    for (int d = 1; d < 256; d <<= 1) {
        int u = (tid >= d) ? t[tid - d] : 0;
        __syncthreads();
        t[tid] += u;
        __syncthreads();
    }
    if (tid < NPB) off[b * NPB + tid] = base + t[tid] - hv;   // exclusive
    __syncthreads();

    for (int sl = tid; sl < count; sl += 256) {
        int2 v = stg[b * BCAP + sl];
        int dl = (unsigned)v.x >> 17;
        int pos = base + (t[dl] - hist[dl]) + atomicAdd(&cur[dl], 1);
        csr[pos] = make_int2(v.x & 0x1ffff, v.y);
    }
}

// ---------------------------------------------------------------------------
// K5: node kernel, 1 wave = 1 node; packed-fp32 (f32x2 -> v_pk_*) math.
// Output written as bf16.
// ---------------------------------------------------------------------------
__global__ __launch_bounds__(256) void node_kernel(
    const unsigned short* __restrict__ xlbf, const float* __restrict__ xr,
    const float* __restrict__ We, const float* __restrict__ att,
    const int* __restrict__ off, const int2* __restrict__ csr,
    unsigned short* __restrict__ out_bf)
{
    const int n = blockIdx.x * 4 + (threadIdx.x >> 6);
    if (n >= NN) return;
    const int l  = threadIdx.x & 63;
    const int g  = l >> 4;
    const int i  = l & 15;
    const int c0 = i * 8;

    f32x2 wev[4], atv[4], xrv[4];
#pragma unroll
    for (int j = 0; j < 4; ++j) {
        wev[j] = (f32x2){We[c0 + 2 * j], We[c0 + 2 * j + 1]};
        atv[j] = (f32x2){att[c0 + 2 * j], att[c0 + 2 * j + 1]};
        xrv[j] = (f32x2){xr[(size_t)n * HCD + c0 + 2 * j],
                         xr[(size_t)n * HCD + c0 + 2 * j + 1]};
    }

    const int s = off[n], e = off[n + 1];
    if (s == e) {
        if (g == 0) {
            uint4 z = make_uint4(0, 0, 0, 0);
            *(uint4*)&out_bf[(size_t)n * HCD + c0] = z;
        }
        return;
    }

    float mx = -3.0e38f, sm = 0.f;
    f32x2 acc[4];
#pragma unroll
    for (int j = 0; j < 4; ++j) acc[j] = (f32x2){0.f, 0.f};

    int k = s;
    int2 c2; uint4 xb; bool v;
    {
        int idx = min(k + g, e - 1);
        c2 = csr[idx];
        xb = *(const uint4*)&xlbf[(size_t)c2.x * HCD + c0];
        v  = (k + g) < e;
    }

    for (; k < e; k += 4) {
        int2 c2n; uint4 xbn; bool vn;
        {
            int idx = min(k + 4 + g, e - 1);
            c2n = csr[idx];
            xbn = *(const uint4*)&xlbf[(size_t)c2n.x * HCD + c0];
            vn  = (k + 4 + g) < e;
        }
        f32x2 xv[4];
        xv[0] = (f32x2){__uint_as_float(xb.x << 16), __uint_as_float(xb.x & 0xffff0000u)};
        xv[1] = (f32x2){__uint_as_float(xb.y << 16), __uint_as_float(xb.y & 0xffff0000u)};
        xv[2] = (f32x2){__uint_as_float(xb.z << 16), __uint_as_float(xb.z & 0xffff0000u)};
        xv[3] = (f32x2){__uint_as_float(xb.w << 16), __uint_as_float(xb.w & 0xffff0000u)};

        float eaf = __int_as_float(c2.y);
        f32x2 p2 = (f32x2){0.f, 0.f};
#pragma unroll
        for (int j = 0; j < 4; ++j) {
            f32x2 s2 = xv[j] + xrv[j];
            s2 = eaf * wev[j] + s2;                       // pk_fma
            f32x2 m2 = __builtin_elementwise_max(s2, s2 * 0.2f);  // leaky_relu
            p2 = m2 * atv[j] + p2;                        // pk_fma
        }
        float p = p2.x + p2.y;
        p += __shfl_xor(p, 1);                            // 4-lane head reduce
        p += __shfl_xor(p, 2);
        if (!v) p = -1.0e30f;

        if (__any(p > mx + 8.f)) {
            float nm = fmaxf(mx, p);
            float sc = __expf(mx - nm);
            sm *= sc;
#pragma unroll
            for (int j = 0; j < 4; ++j) acc[j] *= sc;
            mx = nm;
        }
        float ev = v ? __expf(p - mx) : 0.f;
        sm += ev;
#pragma unroll
        for (int j = 0; j < 4; ++j) acc[j] = ev * xv[j] + acc[j];   // pk_fma

        c2 = c2n; xb = xbn; v = vn;
    }

    // merge the 4 group states (lanes l, l^16, l^32 hold same channels)
    float M = fmaxf(mx, __shfl_xor(mx, 16));
    M = fmaxf(M, __shfl_xor(M, 32));
    float sc = __expf(mx - M);
    float smT = sm * sc;
    smT += __shfl_xor(smT, 16);
    smT += __shfl_xor(smT, 32);
    float inv = 1.f / (smT + 1e-16f);
    unsigned uo[4];
#pragma unroll
    for (int j = 0; j < 4; ++j) {
        float a0 = acc[j].x * sc, a1 = acc[j].y * sc;
        a0 += __shfl_xor(a0, 16);  a0 += __shfl_xor(a0, 32);
        a1 += __shfl_xor(a1, 16);  a1 += __shfl_xor(a1, 32);
        uo[j] = (unsigned)bf16rne(a0 * inv) | ((unsigned)bf16rne(a1 * inv) << 16);
    }
    if (g == 0)
        *(uint4*)&out_bf[(size_t)n * HCD + c0] = make_uint4(uo[0], uo[1], uo[2], uo[3]);
}

// ---------------------------------------------------------------------------
// K6: BN statistics — vectorized uint2 (4ch) loads, shfl+LDS reduction,
// one global atomic per channel per block.
// ---------------------------------------------------------------------------
__global__ __launch_bounds__(256) void bnstat_kernel(const unsigned short* __restrict__ out_bf,
                                                     float* __restrict__ stats)
{
    __shared__ float lsum[HCD], lsq[HCD];
    const int tid = threadIdx.x;
    if (tid < HCD) { lsum[tid] = 0.f; lsq[tid] = 0.f; }
    __syncthreads();

    const int q  = tid & 31;          // channel quad index
    const int c0 = q * 4;
    const int r  = tid >> 5;          // row slot 0..7

    float s[4] = {0.f, 0.f, 0.f, 0.f}, qq[4] = {0.f, 0.f, 0.f, 0.f};
    for (int n = blockIdx.x * 8 + r; n < NN; n += gridDim.x * 8) {
        uint2 u = *(const uint2*)&out_bf[(size_t)n * HCD + c0];
        float v0 = __uint_as_float(u.x << 16);
        float v1 = __uint_as_float(u.x & 0xffff0000u);
        float v2 = __uint_as_float(u.y << 16);
        float v3 = __uint_as_float(u.y & 0xffff0000u);
        s[0] += v0; qq[0] += v0 * v0;
        s[1] += v1; qq[1] += v1 * v1;
        s[2] += v2; qq[2] += v2 * v2;
        s[3] += v3; qq[3] += v3 * v3;
    }
    // lanes l and l^32 share channels -> butterfly, then lanes <32 push to LDS
#pragma unroll
    for (int j = 0; j < 4; ++j) {
        s[j]  += __shfl_xor(s[j], 32);
        qq[j] += __shfl_xor(qq[j], 32);
    }
    if ((tid & 32) == 0) {
#pragma unroll
        for (int j = 0; j < 4; ++j) {
            atomicAdd(&lsum[c0 + j], s[j]);
            atomicAdd(&lsq[c0 + j], qq[j]);
        }
    }
    __syncthreads();
    if (tid < HCD)            atomicAdd(&stats[tid], lsum[tid]);
    else                      atomicAdd(&stats[tid], lsq[tid - HCD]);
}

// ---------------------------------------------------------------------------
// K6b: fold stats -> per-channel scale/shift (1 block)
// ---------------------------------------------------------------------------
__global__ __launch_bounds__(128) void bnprep_kernel(
    const float* __restrict__ stats, const float* __restrict__ gamma,
    const float* __restrict__ beta, float* __restrict__ ss)
{
    int c = threadIdx.x;
    float mean = stats[c] * (1.f / NN);
    float var  = stats[HCD + c] * (1.f / NN) - mean * mean;
    float sc   = gamma[c] * rsqrtf(var + 1e-5f);
    ss[c]       = sc;
    ss[HCD + c] = beta[c] - mean * sc;
}

// ---------------------------------------------------------------------------
// K7: normalize + ELU: one FMA + select + __expf per element.
// bf16 in, fp32 out, 8 channels/thread.
// ---------------------------------------------------------------------------
__global__ __launch_bounds__(256) void bn_elu_kernel(
    const unsigned short* __restrict__ out_bf, const float* __restrict__ ss,
    float* __restrict__ out)
{
    int i8 = blockIdx.x * 256 + threadIdx.x;        // 8 channels per thread
    if (i8 >= NN * HCD / 8) return;
    int c0 = (i8 & 15) * 8;
    uint4 u = *(const uint4*)&out_bf[(size_t)i8 * 8];
    float vv[8] = {
        __uint_as_float(u.x << 16), __uint_as_float(u.x & 0xffff0000u),
        __uint_as_float(u.y << 16), __uint_as_float(u.y & 0xffff0000u),
        __uint_as_float(u.z << 16), __uint_as_float(u.z & 0xffff0000u),
        __uint_as_float(u.w << 16), __uint_as_float(u.w & 0xffff0000u)};
    float o[8];
#pragma unroll
    for (int j = 0; j < 8; ++j) {
        int c = c0 + j;
        float t = fmaf(vv[j], ss[c], ss[HCD + c]);
        o[j] = (t > 0.f) ? t : (__expf(t) - 1.f);
    }
    float* dst = &out[(size_t)i8 * 8];
    *(float4*)dst       = make_float4(o[0], o[1], o[2], o[3]);
    *(float4*)(dst + 4) = make_float4(o[4], o[5], o[6], o[7]);
}

// ---------------------------------------------------------------------------
extern "C" void kernel_launch(void* const* d_in, const int* in_sizes, int n_in,
                              void* d_out, int out_size, void* d_ws, size_t ws_size,
                              hipStream_t stream)
{
    (void)in_sizes; (void)n_in; (void)out_size; (void)ws_size;
    const float* x    = (const float*)d_in[0];
    const int*   ei   = (const int*)  d_in[1];
    const float* ea   = (const float*)d_in[2];
    const float* Wl   = (const float*)d_in[3];
    const float* bl   = (const float*)d_in[4];
    const float* Wr   = (const float*)d_in[5];
    const float* br   = (const float*)d_in[6];
    const float* We   = (const float*)d_in[7];
    const float* att  = (const float*)d_in[8];
    const float* gamma= (const float*)d_in[10];
    const float* beta = (const float*)d_in[11];
    float* out = (float*)d_out;

    char* wsb = (char*)d_ws;
    size_t o = 0;
    auto take = [&](size_t bytes) -> char* {
        char* p = wsb + o;
        o += (bytes + 255) & ~size_t(255);
        return p;
    };
    unsigned short* xlbf  = (unsigned short*)take(sizeof(unsigned short) * NN * HCD);
    float*          xr    = (float*)take(sizeof(float) * NN * HCD);
    unsigned short* outbf = (unsigned short*)take(sizeof(unsigned short) * NN * HCD);
    int2*  csr     = (int2*) take(sizeof(int2)  * NE);
    int*   offs    = (int*)  take(sizeof(int)   * (NN + 1));
    int*   bbase   = (int*)  take(sizeof(int)   * 256);
    int2*  stg     = (int2*) take(sizeof(int2)  * NBKT * BCAP);   // 8.2 MB
    float* ss      = (float*)take(sizeof(float) * 2 * HCD);
    size_t zbytes  = sizeof(float) * 2 * HCD + sizeof(int) * NBKT;
    char*  zbase   = take(zbytes);
    float* stats   = (float*)zbase;
    int*   gcur    = (int*)(stats + 2 * HCD);

    hipMemsetAsync(zbase, 0, zbytes, stream);

    const int* srcI = ei;
    const int* dstI = ei + NE;

    gemm_mfma<<<dim3((NN + BM - 1) / BM, 2), 256, 49152, stream>>>(
        x, Wl, Wr, bl, br, xlbf, xr);
    bucket_kernel<<<B1B, 256, 0, stream>>>(srcI, dstI, ea, gcur, stg);
    bscan<<<1, 256, 0, stream>>>(gcur, bbase, offs);
    csr_build<<<NBKT, 256, 0, stream>>>(stg, gcur, bbase, offs, csr);
    node_kernel<<<(NN + 3) / 4, 256, 0, stream>>>(xlbf, xr, We, att, offs, csr, outbf);
    bnstat_kernel<<<512, 256, 0, stream>>>(outbf, stats);
    bnprep_kernel<<<1, 128, 0, stream>>>(stats, gamma, beta, ss);
    bn_elu_kernel<<<(NN * HCD / 8 + 255) / 256, 256, 0, stream>>>(outbf, ss, out);
}